// Round 13
// baseline (169.597 us; speedup 1.0000x reference)
//
#include <hip/hip_runtime.h>
#include <hip/hip_bf16.h>
#include <stdint.h>

#define EPSBN 1e-5f

typedef float f32x4 __attribute__((ext_vector_type(4)));
typedef __bf16 bf16x8 __attribute__((ext_vector_type(8)));

#define BB 8
#define XCH 1024
#define YCH 512
#define CCH 512
#define PP  4096   // H*W = 64*64

__device__ __forceinline__ unsigned short f2bf(float f) {
    union { float f; uint32_t u; } v; v.f = f;
    uint32_t r = v.u + 0x7fffu + ((v.u >> 16) & 1u);   // RNE
    return (unsigned short)(r >> 16);
}

__device__ __forceinline__ void gload16(const void* g, void* l) {
    __builtin_amdgcn_global_load_lds(
        (__attribute__((address_space(1))) void*)(g),
        (__attribute__((address_space(3))) void*)(l),
        16, 0, 0);
}

// ---------- x [b][k][p] fp32 -> x_t [b][p][k] bf16 (~32us, HBM roofline) ----------
__global__ __launch_bounds__(256)
void k_transpose(const float* __restrict__ x, unsigned short* __restrict__ xt) {
    __shared__ float tile[64][65];
    int bx = blockIdx.x;
    int b = bx >> 10, rem = bx & 1023;
    int k0 = (rem >> 6) << 6, p0 = (rem & 63) << 6;
    int t = threadIdx.x;
    const float* xb = x + ((size_t)b * XCH + k0) * PP + p0;
#pragma unroll
    for (int it = 0; it < 4; ++it) {
        int fi = it * 256 + t;
        int kk = fi >> 4, pp = (fi & 15) << 2;
        float4 v = *(const float4*)(xb + (size_t)kk * PP + pp);
        tile[kk][pp] = v.x; tile[kk][pp + 1] = v.y;
        tile[kk][pp + 2] = v.z; tile[kk][pp + 3] = v.w;
    }
    __syncthreads();
    unsigned short* xtb = xt + ((size_t)b * PP + p0) * XCH + k0;
#pragma unroll
    for (int ot = 0; ot < 2; ++ot) {
        int g = ot * 256 + t;
        int pp = g >> 3, ko = (g & 7) << 3;
        uint32_t u0 = (uint32_t)f2bf(tile[ko + 0][pp]) | ((uint32_t)f2bf(tile[ko + 1][pp]) << 16);
        uint32_t u1 = (uint32_t)f2bf(tile[ko + 2][pp]) | ((uint32_t)f2bf(tile[ko + 3][pp]) << 16);
        uint32_t u2 = (uint32_t)f2bf(tile[ko + 4][pp]) | ((uint32_t)f2bf(tile[ko + 5][pp]) << 16);
        uint32_t u3 = (uint32_t)f2bf(tile[ko + 6][pp]) | ((uint32_t)f2bf(tile[ko + 7][pp]) << 16);
        *(uint4*)(xtb + (size_t)pp * XCH + ko) = make_uint4(u0, u1, u2, u3);
    }
}

// ---------- fused: y_pool (blocks 0..4095) + weight cvt (blocks 4096..4863) ----------
__global__ __launch_bounds__(256)
void k_pre(const float* __restrict__ y, const float* __restrict__ wred, const float* __restrict__ wfus,
           float* __restrict__ ypool, unsigned short* __restrict__ wred_bf, unsigned short* __restrict__ wfus_bf) {
    int bx = blockIdx.x, t = threadIdx.x;
    if (bx < 4096) {
        const float4* base = (const float4*)(y + (size_t)bx * PP);
        float s = 0.f;
#pragma unroll
        for (int it = 0; it < 4; ++it) {
            float4 v = base[t + it * 256];
            s += v.x + v.y + v.z + v.w;
        }
#pragma unroll
        for (int off = 32; off > 0; off >>= 1) s += __shfl_down(s, off);
        __shared__ float wsum[4];
        if ((t & 63) == 0) wsum[t >> 6] = s;
        __syncthreads();
        if (t == 0) ypool[bx] = (wsum[0] + wsum[1] + wsum[2] + wsum[3]) * (1.f / 4096.f);
    } else {
        int idx = (bx - 4096) * 256 + t;                   // < 196608
        const int n1 = CCH * XCH / 4;                      // 131072
        float4 v; unsigned short* dst;
        if (idx < n1) { v = ((const float4*)wred)[idx]; dst = wred_bf + (size_t)idx * 4; }
        else { int j = idx - n1; v = ((const float4*)wfus)[j]; dst = wfus_bf + (size_t)j * 4; }
        *(uint2*)dst = make_uint2(((uint32_t)f2bf(v.x)) | ((uint32_t)f2bf(v.y) << 16),
                                  ((uint32_t)f2bf(v.z)) | ((uint32_t)f2bf(v.w) << 16));
    }
}

// ---------- fused: G (blocks 0..15) + BN-const folding (blocks 16..17) ----------
__global__ __launch_bounds__(256)
void k_gf2(const float* __restrict__ wgen, const float* __restrict__ bgen,
           const float* __restrict__ ggen, const float* __restrict__ begen,
           const float* __restrict__ mgen, const float* __restrict__ vgen,
           const float* __restrict__ ypool,
           const float* g_red, const float* be_red, const float* m_red, const float* v_red, const float* b_red,
           const float* g_act, const float* be_act, const float* m_act, const float* v_act,
           const float* g_fus, const float* be_fus, const float* m_fus, const float* v_fus, const float* b_fus,
           float* __restrict__ G, float* A1, float* B1, float* CACT, float* A2, float* B2) {
    int bx = blockIdx.x, t = threadIdx.x;
    if (bx < 16) {
        int idx = bx * 256 + t;
        int b = idx >> 9, c = idx & 511;
        const float4* wr = (const float4*)(wgen + (size_t)c * YCH);
        const float4* yp = (const float4*)(ypool + b * YCH);
        float dot = 0.f;
        for (int k = 0; k < YCH / 4; ++k) {
            float4 w = wr[k], v = yp[k];
            dot += w.x * v.x + w.y * v.y + w.z * v.z + w.w * v.w;
        }
        float ag = ggen[c] * rsqrtf(vgen[c] + EPSBN);
        float gf = fmaxf(ag * (dot + bgen[c] - mgen[c]) + begen[c], 0.f);
        float aa = g_act[c] * rsqrtf(v_act[c] + EPSBN);
        G[idx] = aa * gf;
    } else {
        int c = (bx - 16) * 256 + t;
        if (c >= CCH) return;
        float a1 = g_red[c] * rsqrtf(v_red[c] + EPSBN);
        A1[c] = a1;
        B1[c] = a1 * (b_red[c] - m_red[c]) + be_red[c];
        float aa = g_act[c] * rsqrtf(v_act[c] + EPSBN);
        CACT[c] = be_act[c] - aa * m_act[c];
        float a2 = g_fus[c] * rsqrtf(v_fus[c] + EPSBN);
        A2[c] = a2;
        B2[c] = a2 * (b_fus[c] - m_fus[c]) + be_fus[c];
    }
}

// ============================================================================
// GEMM1 on xt: h[b][p][c] = epi( xt[b][p][:] . wred_bf[c][:] )
// 256x256 block tile, 4 waves, WAVE TILE 128x128 (acc 8x8 f32x4 = 256 VGPR),
// BK=32, NT=32, 3-buf depth-2 counted vmcnt(8). LDS 3x32KB = 96KB, 1 block/CU,
// grid = 256 blocks (exactly one per CU, single-shot).
// LDS/FLOP = 0.0229 B/F (vs 0.0343 R12, 0.0457 R11) -- the traffic lever.
// ============================================================================
__global__ __launch_bounds__(256, 1)
void k_gemm1(const unsigned short* __restrict__ At, const unsigned short* __restrict__ Bt,
             unsigned short* __restrict__ H,
             const float* __restrict__ C0, const float* __restrict__ C1,
             const float* __restrict__ C2, const float* __restrict__ G) {
    __shared__ __align__(16) char sm[98304];
    constexpr int NT = 32;      // K=1024 / BK=32
    constexpr int KE = 1024;

    // 256 blocks -> 32 consecutive per XCD; n fastest (A-panel shared by n-pair)
    int r = blockIdx.x + (blockIdx.y << 1) + (blockIdx.z << 5);
    int w = ((r & 7) << 5) | (r >> 3);
    const int n0 = (w & 1) << 8;          // c-tile (256)
    const int m0 = ((w >> 1) & 15) << 8;  // p-tile (256)
    const int bz = w >> 5;

    const int t = threadIdx.x;
    const int lane = t & 63, wave = t >> 6;
    const int l15 = lane & 15, l4v = lane >> 4;
    const int wm = wave >> 1, wn = wave & 1;

    // staging: operand tile = 256 rows x 64B; 4 gload rounds/operand.
    // q-stride: du += 256 -> row += 64 -> m2 unchanged -> src += 64*KE, dst += 4096.
    const unsigned short* Abase = At + (size_t)bz * ((size_t)PP * KE) + (size_t)m0 * KE;
    const unsigned short* Bbase = Bt + (size_t)n0 * KE;
    int du = (wave << 6) + lane;
    int row0 = du >> 2, g0 = du & 3;
    int m20 = (row0 >> 1) & 3;
    const unsigned short* pA0 = Abase + (size_t)row0 * KE + ((g0 ^ m20) << 3);
    const unsigned short* pB0 = Bbase + (size_t)row0 * KE + ((g0 ^ m20) << 3);
    const int sd0 = (wave << 6) << 4;     // wave-uniform dest base (bytes)

    // frag read offsets: m2 invariant across i (row step 16 -> row>>1 step 8 -> &3 same)
    int rowA0 = (wm << 7) + l15;
    int offA0 = rowA0 * 64 + ((l4v ^ ((rowA0 >> 1) & 3)) << 4);
    int rowB0 = (wn << 7) + l15;
    int offB0 = rowB0 * 64 + ((l4v ^ ((rowB0 >> 1) & 3)) << 4);

#define STAGE1(tt, b3_) { char* dA_ = sm + (b3_) * 32768; char* dB_ = dA_ + 16384; \
        gload16(pA0 + (tt) * 32,           dA_ + sd0); \
        gload16(pA0 + (tt) * 32 + 65536,   dA_ + sd0 + 4096); \
        gload16(pA0 + (tt) * 32 + 131072,  dA_ + sd0 + 8192); \
        gload16(pA0 + (tt) * 32 + 196608,  dA_ + sd0 + 12288); \
        gload16(pB0 + (tt) * 32,           dB_ + sd0); \
        gload16(pB0 + (tt) * 32 + 65536,   dB_ + sd0 + 4096); \
        gload16(pB0 + (tt) * 32 + 131072,  dB_ + sd0 + 8192); \
        gload16(pB0 + (tt) * 32 + 196608,  dB_ + sd0 + 12288); }

    f32x4 acc[8][8];
#pragma unroll
    for (int i = 0; i < 8; ++i)
#pragma unroll
        for (int j = 0; j < 8; ++j) acc[i][j] = (f32x4){0.f, 0.f, 0.f, 0.f};

    STAGE1(0, 0)
    STAGE1(1, 1)
    asm volatile("s_waitcnt vmcnt(8)" ::: "memory");   // S(0) landed
    __builtin_amdgcn_s_barrier();

    int b3 = 0;
    for (int tk = 0; tk < NT; ++tk) {
        char* aB = sm + b3 * 32768 + offA0;
        char* bB = sm + b3 * 32768 + 16384 + offB0;
        bf16x8 af[8], bf_[8];
#pragma unroll
        for (int i = 0; i < 8; ++i) af[i] = *(const bf16x8*)(aB + (i << 10));
#pragma unroll
        for (int j = 0; j < 8; ++j) bf_[j] = *(const bf16x8*)(bB + (j << 10));
        if (tk + 2 < NT) {
            int nb = b3 - 1; if (nb < 0) nb += 3;
            STAGE1(tk + 2, nb)
        }
#pragma unroll
        for (int i = 0; i < 8; ++i)
#pragma unroll
            for (int j = 0; j < 8; ++j)
                acc[i][j] = __builtin_amdgcn_mfma_f32_16x16x32_bf16(af[i], bf_[j], acc[i][j], 0, 0, 0);
        if (tk < NT - 2) {
            asm volatile("s_waitcnt vmcnt(8)" ::: "memory");   // S(tk+1) landed
            __builtin_amdgcn_s_barrier();
        } else if (tk == NT - 2) {
            asm volatile("s_waitcnt vmcnt(0)" ::: "memory");
            __builtin_amdgcn_s_barrier();
        }
        b3 = (b3 == 2) ? 0 : b3 + 1;
    }
#undef STAGE1

    // epilogue: relu(bn_red) * G + CACT, relu -> bf16 h[p][c]
    unsigned short* Ob = H + (size_t)bz * ((size_t)PP * CCH);
    const float* Gb = G + (size_t)bz * CCH;
#pragma unroll
    for (int j = 0; j < 8; ++j) {
        int c = n0 + (wn << 7) + (j << 4) + l15;
        float a1c = C0[c], b1c = C1[c], cac = C2[c], gc = Gb[c];
#pragma unroll
        for (int i = 0; i < 8; ++i) {
            int pr = m0 + (wm << 7) + (i << 4) + (l4v << 2);
#pragma unroll
            for (int q = 0; q < 4; ++q) {
                float xr = fmaxf(a1c * acc[i][j][q] + b1c, 0.f);
                float hv = fmaxf(gc * xr + cac, 0.f);
                Ob[(size_t)(pr + q) * CCH + c] = f2bf(hv);
            }
        }
    }
}

// ============================================================================
// GEMM2: out[b][c][p] = relu(bn_fus(wfus . h))
// A = wfus_bf [c][k] KE=512, B = h [b][p][k]. Same 256x256 / 128x128-wave
// skeleton, BK=32, NT=16. Grid 256 blocks (1/CU). m fastest (B-panel shared).
// ============================================================================
__global__ __launch_bounds__(256, 1)
void k_gemm2(const unsigned short* __restrict__ A, const unsigned short* __restrict__ Bt,
             float* __restrict__ Out,
             const float* __restrict__ C0, const float* __restrict__ C1) {
    __shared__ __align__(16) char sm[98304];
    constexpr int NT = 16;      // K=512 / BK=32
    constexpr int KE = 512;

    int r = blockIdx.x + (blockIdx.y << 4) + (blockIdx.z << 5);
    int w = ((r & 7) << 5) | (r >> 3);
    const int m0 = (w & 1) << 8;          // c-tile (256)
    const int n0 = ((w >> 1) & 15) << 8;  // p-tile (256)
    const int bz = w >> 5;

    const int t = threadIdx.x;
    const int lane = t & 63, wave = t >> 6;
    const int l15 = lane & 15, l4v = lane >> 4;
    const int wm = wave >> 1, wn = wave & 1;

    const unsigned short* Abase = A + (size_t)m0 * KE;
    const unsigned short* Bbase = Bt + (size_t)bz * ((size_t)PP * CCH) + (size_t)n0 * KE;
    int du = (wave << 6) + lane;
    int row0 = du >> 2, g0 = du & 3;
    int m20 = (row0 >> 1) & 3;
    const unsigned short* pA0 = Abase + (size_t)row0 * KE + ((g0 ^ m20) << 3);
    const unsigned short* pB0 = Bbase + (size_t)row0 * KE + ((g0 ^ m20) << 3);
    const int sd0 = (wave << 6) << 4;

    int rowA0 = (wm << 7) + l15;
    int offA0 = rowA0 * 64 + ((l4v ^ ((rowA0 >> 1) & 3)) << 4);
    int rowB0 = (wn << 7) + l15;
    int offB0 = rowB0 * 64 + ((l4v ^ ((rowB0 >> 1) & 3)) << 4);

#define STAGE2(tt, b3_) { char* dA_ = sm + (b3_) * 32768; char* dB_ = dA_ + 16384; \
        gload16(pA0 + (tt) * 32,           dA_ + sd0); \
        gload16(pA0 + (tt) * 32 + 32768,   dA_ + sd0 + 4096); \
        gload16(pA0 + (tt) * 32 + 65536,   dA_ + sd0 + 8192); \
        gload16(pA0 + (tt) * 32 + 98304,   dA_ + sd0 + 12288); \
        gload16(pB0 + (tt) * 32,           dB_ + sd0); \
        gload16(pB0 + (tt) * 32 + 32768,   dB_ + sd0 + 4096); \
        gload16(pB0 + (tt) * 32 + 65536,   dB_ + sd0 + 8192); \
        gload16(pB0 + (tt) * 32 + 98304,   dB_ + sd0 + 12288); }

    f32x4 acc[8][8];
#pragma unroll
    for (int i = 0; i < 8; ++i)
#pragma unroll
        for (int j = 0; j < 8; ++j) acc[i][j] = (f32x4){0.f, 0.f, 0.f, 0.f};

    STAGE2(0, 0)
    STAGE2(1, 1)
    asm volatile("s_waitcnt vmcnt(8)" ::: "memory");
    __builtin_amdgcn_s_barrier();

    int b3 = 0;
    for (int tk = 0; tk < NT; ++tk) {
        char* aB = sm + b3 * 32768 + offA0;
        char* bB = sm + b3 * 32768 + 16384 + offB0;
        bf16x8 af[8], bf_[8];
#pragma unroll
        for (int i = 0; i < 8; ++i) af[i] = *(const bf16x8*)(aB + (i << 10));
#pragma unroll
        for (int j = 0; j < 8; ++j) bf_[j] = *(const bf16x8*)(bB + (j << 10));
        if (tk + 2 < NT) {
            int nb = b3 - 1; if (nb < 0) nb += 3;
            STAGE2(tk + 2, nb)
        }
#pragma unroll
        for (int i = 0; i < 8; ++i)
#pragma unroll
            for (int j = 0; j < 8; ++j)
                acc[i][j] = __builtin_amdgcn_mfma_f32_16x16x32_bf16(af[i], bf_[j], acc[i][j], 0, 0, 0);
        if (tk < NT - 2) {
            asm volatile("s_waitcnt vmcnt(8)" ::: "memory");
            __builtin_amdgcn_s_barrier();
        } else if (tk == NT - 2) {
            asm volatile("s_waitcnt vmcnt(0)" ::: "memory");
            __builtin_amdgcn_s_barrier();
        }
        b3 = (b3 == 2) ? 0 : b3 + 1;
    }
#undef STAGE2

    // epilogue: fp32 out, BN_fus + ReLU; out[b][c][p]
    float* Ob = Out + (size_t)bz * ((size_t)CCH * PP);
#pragma unroll
    for (int i = 0; i < 8; ++i) {
#pragma unroll
        for (int q = 0; q < 4; ++q) {
            int orow = m0 + (wm << 7) + (i << 4) + (l4v << 2) + q;
            float a2 = C0[orow], b2 = C1[orow];
#pragma unroll
            for (int j = 0; j < 8; ++j) {
                int pc = n0 + (wn << 7) + (j << 4) + l15;
                Ob[(size_t)orow * PP + pc] = fmaxf(a2 * acc[i][j][q] + b2, 0.f);
            }
        }
    }
}

extern "C" void kernel_launch(void* const* d_in, const int* in_sizes, int n_in,
                              void* d_out, int out_size, void* d_ws, size_t ws_size,
                              hipStream_t stream) {
    const float* x      = (const float*)d_in[0];
    const float* y      = (const float*)d_in[1];
    const float* w_red  = (const float*)d_in[2];
    const float* b_red  = (const float*)d_in[3];
    const float* g_red  = (const float*)d_in[4];
    const float* be_red = (const float*)d_in[5];
    const float* m_red  = (const float*)d_in[6];
    const float* v_red  = (const float*)d_in[7];
    const float* w_gen  = (const float*)d_in[8];
    const float* b_gen  = (const float*)d_in[9];
    const float* g_gen  = (const float*)d_in[10];
    const float* be_gen = (const float*)d_in[11];
    const float* m_gen  = (const float*)d_in[12];
    const float* v_gen  = (const float*)d_in[13];
    const float* g_act  = (const float*)d_in[14];
    const float* be_act = (const float*)d_in[15];
    const float* m_act  = (const float*)d_in[16];
    const float* v_act  = (const float*)d_in[17];
    const float* w_fus  = (const float*)d_in[18];
    const float* b_fus  = (const float*)d_in[19];
    const float* g_fus  = (const float*)d_in[20];
    const float* be_fus = (const float*)d_in[21];
    const float* m_fus  = (const float*)d_in[22];
    const float* v_fus  = (const float*)d_in[23];

    // workspace layout (bytes)
    const size_t off_xt   = 0;                          // 67108864
    const size_t off_h    = 67108864;                   // 33554432
    const size_t off_wred = 100663296;                  // 1048576
    const size_t off_wfus = 101711872;                  // 524288
    const size_t off_pool = 102236160;                  // 16384
    const size_t off_G    = 102252544;                  // 16384
    const size_t off_cst  = 102268928;                  // 6*2048
    const size_t need     = off_cst + 6 * 2048;
    if (ws_size < need) return;

    char* ws = (char*)d_ws;
    unsigned short* xt      = (unsigned short*)(ws + off_xt);
    unsigned short* h       = (unsigned short*)(ws + off_h);
    unsigned short* wred_bf = (unsigned short*)(ws + off_wred);
    unsigned short* wfus_bf = (unsigned short*)(ws + off_wfus);
    float* ypool = (float*)(ws + off_pool);
    float* G     = (float*)(ws + off_G);
    float* A1    = (float*)(ws + off_cst);
    float* B1    = A1 + 512;
    float* CACT  = B1 + 512;
    float* A2    = CACT + 512;
    float* B2    = A2 + 512;

    k_transpose<<<8192, 256, 0, stream>>>(x, xt);
    k_pre<<<4864, 256, 0, stream>>>(y, w_red, w_fus, ypool, wred_bf, wfus_bf);
    k_gf2<<<18, 256, 0, stream>>>(w_gen, b_gen, g_gen, be_gen, m_gen, v_gen, ypool,
                                  g_red, be_red, m_red, v_red, b_red,
                                  g_act, be_act, m_act, v_act,
                                  g_fus, be_fus, m_fus, v_fus, b_fus,
                                  G, A1, B1, CACT, A2, B2);

    dim3 g1(2, 16, 8);   // n=512/256 (c), m=4096/256 (p), batch
    k_gemm1<<<g1, 256, 0, stream>>>(xt, wred_bf, h, A1, B1, CACT, G);
    dim3 g2(16, 2, 8);   // n=4096/256 (p), m=512/256 (c), batch
    k_gemm2<<<g2, 256, 0, stream>>>(wfus_bf, h, (float*)d_out, A2, B2);
}